// Round 1
// baseline (2032.003 us; speedup 1.0000x reference)
//
#include <hip/hip_runtime.h>
#include <hip/hip_bf16.h>
#include <math.h>

#define BT 32768        // B*T tokens
#define HH 1024

typedef unsigned short u16;
typedef __attribute__((ext_vector_type(4))) unsigned short u16x4;
typedef __attribute__((ext_vector_type(8))) __bf16 bf16x8;
typedef __attribute__((ext_vector_type(4))) float f32x4;

#define DEVI static __device__ __forceinline__

DEVI u16 f2bf(float f){
  unsigned u = __builtin_bit_cast(unsigned, f);
  u += 0x7FFFu + ((u >> 16) & 1u);
  return (u16)(u >> 16);
}
DEVI float bf2f(u16 h){
  unsigned u = ((unsigned)h) << 16;
  return __builtin_bit_cast(float, u);
}
DEVI void gl_lds16(const void* g, void* l){
  __builtin_amdgcn_global_load_lds((const __attribute__((address_space(1))) void*)g,
                                   (__attribute__((address_space(3))) void*)l, 16, 0, 0);
}

// ---------------- elementwise prep kernels ----------------
__global__ void k_cast4(const float* __restrict__ s, u16* __restrict__ d, int n4){
  int i = blockIdx.x*blockDim.x + threadIdx.x;
  int st = gridDim.x*blockDim.x;
  for (; i < n4; i += st){
    float4 v = ((const float4*)s)[i];
    u16x4 o = { f2bf(v.x), f2bf(v.y), f2bf(v.z), f2bf(v.w) };
    ((u16x4*)d)[i] = o;
  }
}

// x2 -> stacked slot 2 (ld 3072)
__global__ void k_pack_x2(const float* __restrict__ s, u16* __restrict__ d, int n4){
  int i = blockIdx.x*blockDim.x + threadIdx.x;
  int st = gridDim.x*blockDim.x;
  for (; i < n4; i += st){
    int e = i*4; int t = e >> 10; int c = e & 1023;
    float4 v = *(const float4*)&s[e];
    u16x4 o = { f2bf(v.x), f2bf(v.y), f2bf(v.z), f2bf(v.w) };
    *(u16x4*)&d[(size_t)t*3072 + 2048 + c] = o;
  }
}

// qb = bf16(query_token + static_context)
__global__ void k_qb(const float* __restrict__ qt, const float* __restrict__ sc,
                     u16* __restrict__ d, int n4){
  int i = blockIdx.x*blockDim.x + threadIdx.x;
  int st = gridDim.x*blockDim.x;
  for (; i < n4; i += st){
    int e = i*4; int c = e & 1023;
    float4 v = *(const float4*)&sc[e];
    float4 q = *(const float4*)&qt[c];
    u16x4 o = { f2bf(v.x+q.x), f2bf(v.y+q.y), f2bf(v.z+q.z), f2bf(v.w+q.w) };
    ((u16x4*)d)[i] = o;
  }
}

__global__ void k_copyf(const float* __restrict__ s, float* __restrict__ d, int n){
  int i = blockIdx.x*blockDim.x + threadIdx.x;
  int st = gridDim.x*blockDim.x;
  for (; i < n; i += st) d[i] = s[i];
}

// ---------------- GEMM: C[M,N](bf16) = A[M,K](bf16) @ B[N,K]^T + bias, opt gelu ----------------
__global__ __launch_bounds__(256, 2)
void k_gemm(const u16* __restrict__ A, int lda,
            const u16* __restrict__ B, int ldb, int K,
            const float* __restrict__ bias,
            u16* __restrict__ C, int ldc, int col0, int act)
{
  __shared__ u16 As[128*64];
  __shared__ u16 Bs[128*64];
  const int tid = threadIdx.x, lane = tid & 63, wid = tid >> 6;
  const int wr = wid >> 1, wc = wid & 1;
  const int r15 = lane & 15, g = lane >> 4;
  const int m0 = blockIdx.x * 128, n0 = blockIdx.y * 128;
  f32x4 acc[4][4] = {};

  for (int k0 = 0; k0 < K; k0 += 64){
    #pragma unroll
    for (int it = 0; it < 4; ++it){
      int c = it*256 + tid;
      int row = c >> 3, kk = (c & 7) * 8;
      gl_lds16(A + (size_t)(m0+row)*lda + (k0+kk), As + c*8);
      gl_lds16(B + (size_t)(n0+row)*ldb + (k0+kk), Bs + c*8);
    }
    __syncthreads();
    #pragma unroll
    for (int kk = 0; kk < 64; kk += 32){
      bf16x8 av[4], bvv[4];
      #pragma unroll
      for (int i = 0; i < 4; ++i)
        av[i] = *(const bf16x8*)&As[(wr*64 + i*16 + r15)*64 + kk + g*8];
      #pragma unroll
      for (int j = 0; j < 4; ++j)
        bvv[j] = *(const bf16x8*)&Bs[(wc*64 + j*16 + r15)*64 + kk + g*8];
      #pragma unroll
      for (int i = 0; i < 4; ++i)
        #pragma unroll
        for (int j = 0; j < 4; ++j)
          acc[i][j] = __builtin_amdgcn_mfma_f32_16x16x32_bf16(av[i], bvv[j], acc[i][j], 0, 0, 0);
    }
    __syncthreads();
  }
  #pragma unroll
  for (int j = 0; j < 4; ++j){
    int col = wc*64 + j*16 + r15;
    float bb = bias ? bias[n0 + col] : 0.f;
    #pragma unroll
    for (int i = 0; i < 4; ++i){
      #pragma unroll
      for (int jj = 0; jj < 4; ++jj){
        int row = wr*64 + i*16 + g*4 + jj;
        float v = acc[i][j][jj] + bb;
        if (act == 1) v = 0.5f * v * (1.f + erff(v * 0.70710678118654752f));
        C[(size_t)(m0+row)*ldc + col0 + n0 + col] = f2bf(v);
      }
    }
  }
}

// ---------------- fused K/V projection + M=3 cross-attention ----------------
// block: 32 tokens (96 stacked rows) x 128 cols (2 heads). K,V GEMM tiles in regs,
// then scores -> softmax over 3 modalities -> ctx + head-mean weights in epilogue.
__global__ __launch_bounds__(256, 2)
void k_attn(const u16* __restrict__ S, const u16* __restrict__ Wk, const u16* __restrict__ Wv,
            const float* __restrict__ bk, const float* __restrict__ bv,
            const u16* __restrict__ Q, u16* __restrict__ ctx, float* __restrict__ wacc)
{
  __shared__ __align__(16) char smem[45056];
  u16* As  = (u16*)smem;                    // 96x64
  u16* Bk  = (u16*)(smem + 12288);          // 128x64
  u16* Bv  = (u16*)(smem + 12288 + 16384);  // 128x64
  u16* Vl  = (u16*)smem;                    // epilogue: 96x128 bf16
  u16* Ql  = (u16*)(smem + 24576);          // epilogue: 32x128 bf16
  float* Sl = (float*)(smem + 24576 + 8192);// epilogue: 2 heads x 96 rows

  const int tid = threadIdx.x, lane = tid & 63, wid = tid >> 6;
  const int wr = wid >> 1, wcH = wid & 1;
  const int r15 = lane & 15, g = lane >> 4;
  const int bt = blockIdx.x, bn = blockIdx.y;
  const int row0 = bt * 96, n0 = bn * 128;

  f32x4 aK[3][4] = {}; f32x4 aV[3][4] = {};

  for (int k0 = 0; k0 < 1024; k0 += 64){
    #pragma unroll
    for (int it = 0; it < 3; ++it){
      int c = it*256 + tid; int row = c >> 3, kk = (c & 7)*8;
      gl_lds16(S + (size_t)(row0+row)*1024 + k0 + kk, As + c*8);
    }
    #pragma unroll
    for (int it = 0; it < 4; ++it){
      int c = it*256 + tid; int row = c >> 3, kk = (c & 7)*8;
      gl_lds16(Wk + (size_t)(n0+row)*1024 + k0 + kk, Bk + c*8);
      gl_lds16(Wv + (size_t)(n0+row)*1024 + k0 + kk, Bv + c*8);
    }
    __syncthreads();
    #pragma unroll
    for (int kk = 0; kk < 64; kk += 32){
      bf16x8 av[3], b1[4], b2[4];
      #pragma unroll
      for (int i = 0; i < 3; ++i)
        av[i] = *(const bf16x8*)&As[(wr*48 + i*16 + r15)*64 + kk + g*8];
      #pragma unroll
      for (int j = 0; j < 4; ++j){
        b1[j] = *(const bf16x8*)&Bk[(wcH*64 + j*16 + r15)*64 + kk + g*8];
        b2[j] = *(const bf16x8*)&Bv[(wcH*64 + j*16 + r15)*64 + kk + g*8];
      }
      #pragma unroll
      for (int i = 0; i < 3; ++i)
        #pragma unroll
        for (int j = 0; j < 4; ++j){
          aK[i][j] = __builtin_amdgcn_mfma_f32_16x16x32_bf16(av[i], b1[j], aK[i][j], 0, 0, 0);
          aV[i][j] = __builtin_amdgcn_mfma_f32_16x16x32_bf16(av[i], b2[j], aV[i][j], 0, 0, 0);
        }
    }
    __syncthreads();
  }

  // V (+bias) -> LDS as bf16
  #pragma unroll
  for (int j = 0; j < 4; ++j){
    int col = wcH*64 + j*16 + r15;
    float bvv = bv[n0 + col];
    #pragma unroll
    for (int i = 0; i < 3; ++i)
      #pragma unroll
      for (int jj = 0; jj < 4; ++jj){
        int row = wr*48 + i*16 + g*4 + jj;
        Vl[row*128 + col] = f2bf(aV[i][j][jj] + bvv);
      }
  }
  // stage Q tile [32 tokens][128 cols]
  #pragma unroll
  for (int it = 0; it < 4; ++it){
    int c4 = it*256 + tid;              // 1024 chunks of 4 elems
    int tt = c4 >> 5, cc = (c4 & 31)*4;
    *(u16x4*)&Ql[tt*128 + cc] = *(const u16x4*)&Q[(size_t)(bt*32 + tt)*1024 + n0 + cc];
  }
  __syncthreads();

  // scores: s[row] = (Q[t,h,:] . (K[row,:]+bk)) / 8 ; d-reduction over 4 col-frags + 16 lanes
  float bkv[4];
  #pragma unroll
  for (int j = 0; j < 4; ++j) bkv[j] = bk[n0 + wcH*64 + j*16 + r15];
  #pragma unroll
  for (int i = 0; i < 3; ++i){
    #pragma unroll
    for (int jj = 0; jj < 4; ++jj){
      int row = wr*48 + i*16 + g*4 + jj;   // 0..95
      int tt = row / 3;
      float s = 0.f;
      #pragma unroll
      for (int j = 0; j < 4; ++j){
        float qv = bf2f(Ql[tt*128 + wcH*64 + j*16 + r15]);
        s += (aK[i][j][jj] + bkv[j]) * qv;
      }
      s += __shfl_xor(s, 1); s += __shfl_xor(s, 2);
      s += __shfl_xor(s, 4); s += __shfl_xor(s, 8);
      if (r15 == 0) Sl[wcH*96 + row] = s * 0.125f;
    }
  }
  __syncthreads();

  // softmax over m=3, ctx, head-averaged weights
  const int t0 = bt*32;
  #pragma unroll
  for (int it = 0; it < 16; ++it){
    int idx = it*256 + tid;
    int tt = idx >> 7, col = idx & 127;
    int h = col >> 6;
    float s0 = Sl[h*96 + tt*3 + 0];
    float s1 = Sl[h*96 + tt*3 + 1];
    float s2 = Sl[h*96 + tt*3 + 2];
    float mx = fmaxf(s0, fmaxf(s1, s2));
    float e0 = expf(s0-mx), e1 = expf(s1-mx), e2 = expf(s2-mx);
    float inv = 1.f/(e0+e1+e2);
    e0 *= inv; e1 *= inv; e2 *= inv;
    float c = e0*bf2f(Vl[(tt*3+0)*128 + col])
            + e1*bf2f(Vl[(tt*3+1)*128 + col])
            + e2*bf2f(Vl[(tt*3+2)*128 + col]);
    ctx[(size_t)(t0+tt)*1024 + n0 + col] = f2bf(c);
    if ((col & 63) == 0){
      atomicAdd(&wacc[(size_t)(t0+tt)*3 + 0], e0*0.0625f);
      atomicAdd(&wacc[(size_t)(t0+tt)*3 + 1], e1*0.0625f);
      atomicAdd(&wacc[(size_t)(t0+tt)*3 + 2], e2*0.0625f);
    }
  }
}

// ---------------- LayerNorm (H=1024), optional bf16 residual, bf16 or f32 out ----------------
__global__ __launch_bounds__(256)
void k_ln(const u16* __restrict__ X, const u16* __restrict__ R,
          const float* __restrict__ gam, const float* __restrict__ bet,
          u16* __restrict__ outb, float* __restrict__ outf)
{
  __shared__ float rs[4], rq[4];
  const int t = blockIdx.x, tid = threadIdx.x;
  const size_t base = (size_t)t*1024 + tid*4;
  u16x4 xv = *(const u16x4*)&X[base];
  float v[4];
  #pragma unroll
  for (int i = 0; i < 4; ++i) v[i] = bf2f(xv[i]);
  if (R){
    u16x4 rv = *(const u16x4*)&R[base];
    #pragma unroll
    for (int i = 0; i < 4; ++i) v[i] += bf2f(rv[i]);
  }
  float s = v[0]+v[1]+v[2]+v[3];
  float q = v[0]*v[0]+v[1]*v[1]+v[2]*v[2]+v[3]*v[3];
  #pragma unroll
  for (int m = 1; m < 64; m <<= 1){ s += __shfl_xor(s, m); q += __shfl_xor(q, m); }
  if ((tid & 63) == 0){ rs[tid>>6] = s; rq[tid>>6] = q; }
  __syncthreads();
  s = rs[0]+rs[1]+rs[2]+rs[3];
  q = rq[0]+rq[1]+rq[2]+rq[3];
  float mean = s * (1.f/1024.f);
  float var  = q * (1.f/1024.f) - mean*mean;
  float rstd = rsqrtf(var + 1e-5f);
  int c0 = tid*4;
  if (outb){
    u16x4 o;
    #pragma unroll
    for (int i = 0; i < 4; ++i) o[i] = f2bf((v[i]-mean)*rstd*gam[c0+i] + bet[c0+i]);
    *(u16x4*)&outb[base] = o;
  } else {
    float4 o;
    o.x = (v[0]-mean)*rstd*gam[c0+0] + bet[c0+0];
    o.y = (v[1]-mean)*rstd*gam[c0+1] + bet[c0+1];
    o.z = (v[2]-mean)*rstd*gam[c0+2] + bet[c0+2];
    o.w = (v[3]-mean)*rstd*gam[c0+3] + bet[c0+3];
    *(float4*)&outf[base] = o;
  }
}

// ---------------- host launcher ----------------
extern "C" void kernel_launch(void* const* d_in, const int* in_sizes, int n_in,
                              void* d_out, int out_size, void* d_ws, size_t ws_size,
                              hipStream_t stream)
{
  (void)in_sizes; (void)n_in; (void)out_size;
  const float* x0  = (const float*)d_in[0];
  const float* x1  = (const float*)d_in[1];
  const float* x2  = (const float*)d_in[2];
  const float* sc  = (const float*)d_in[3];
  const float* Wp0 = (const float*)d_in[4];  const float* bp0 = (const float*)d_in[5];
  const float* Wp1 = (const float*)d_in[6];  const float* bp1 = (const float*)d_in[7];
  const float* Wq  = (const float*)d_in[8];  const float* bq  = (const float*)d_in[9];
  const float* Wk  = (const float*)d_in[10]; const float* bk  = (const float*)d_in[11];
  const float* Wv  = (const float*)d_in[12]; const float* bv  = (const float*)d_in[13];
  const float* Wo  = (const float*)d_in[14]; const float* bo  = (const float*)d_in[15];
  const float* qt  = (const float*)d_in[16];
  const float* g1  = (const float*)d_in[17]; const float* be1 = (const float*)d_in[18];
  const float* g2  = (const float*)d_in[19]; const float* be2 = (const float*)d_in[20];
  const float* W1  = (const float*)d_in[21]; const float* b1  = (const float*)d_in[22];
  const float* W2  = (const float*)d_in[23]; const float* b2  = (const float*)d_in[24];

  char* ws = (char*)d_ws;
  size_t off = 0;
  auto alloc = [&](size_t b)->char*{ char* p = ws + off; off += (b + 255) & ~(size_t)255; return p; };

  u16* Wp0b = (u16*)alloc((size_t)1024*256*2);
  u16* Wp1b = (u16*)alloc((size_t)1024*512*2);
  u16* Wqb  = (u16*)alloc((size_t)1024*1024*2);
  u16* Wkb  = (u16*)alloc((size_t)1024*1024*2);
  u16* Wvb  = (u16*)alloc((size_t)1024*1024*2);
  u16* Wob  = (u16*)alloc((size_t)1024*1024*2);
  u16* W1b  = (u16*)alloc((size_t)4096*1024*2);
  u16* W2b  = (u16*)alloc((size_t)1024*4096*2);
  char* stackedR = alloc((size_t)3*BT*1024*2);   // stacked [3T,1024]; later ff1 chunk
  char* regA = alloc((size_t)BT*1024*2);         // x0b+x1b -> Qb -> attn_out -> ff2
  char* regB = alloc((size_t)BT*1024*2);         // qb -> ctx -> fused1
  float* wacc = (float*)alloc((size_t)BT*3*4);
  if (off > ws_size) return;  // workspace too small; fail visibly

  u16* stackedb = (u16*)stackedR;
  u16* ff1c = (u16*)stackedR;
  u16* x0b = (u16*)regA;
  u16* x1b = (u16*)(regA + (size_t)BT*256*2);
  u16* Qb  = (u16*)regA;
  u16* aob = (u16*)regA;
  u16* ff2b = (u16*)regA;
  u16* qb  = (u16*)regB;
  u16* ctxb = (u16*)regB;
  u16* f1b = (u16*)regB;

  hipMemsetAsync(wacc, 0, (size_t)BT*3*4, stream);

  dim3 B256(256);
  auto cast4 = [&](const float* s, u16* d, int n){
    k_cast4<<<dim3(1024), B256, 0, stream>>>(s, d, n >> 2);
  };
  cast4(Wp0, Wp0b, 1024*256); cast4(Wp1, Wp1b, 1024*512);
  cast4(Wq, Wqb, 1024*1024);  cast4(Wk, Wkb, 1024*1024);
  cast4(Wv, Wvb, 1024*1024);  cast4(Wo, Wob, 1024*1024);
  cast4(W1, W1b, 4096*1024);  cast4(W2, W2b, 4096*1024);
  cast4(x0, x0b, BT*256);     cast4(x1, x1b, BT*512);
  k_pack_x2<<<dim3(2048), B256, 0, stream>>>(x2, stackedb, BT*256);
  k_qb<<<dim3(2048), B256, 0, stream>>>(qt, sc, qb, BT*256);

  k_gemm<<<dim3(BT/128, 8), B256, 0, stream>>>(x0b, 256, Wp0b, 256, 256, bp0, stackedb, 3072, 0,    0);
  k_gemm<<<dim3(BT/128, 8), B256, 0, stream>>>(x1b, 512, Wp1b, 512, 512, bp1, stackedb, 3072, 1024, 0);
  k_gemm<<<dim3(BT/128, 8), B256, 0, stream>>>(qb, 1024, Wqb, 1024, 1024, bq, Qb, 1024, 0, 0);
  k_attn<<<dim3(BT/32, 8), B256, 0, stream>>>(stackedb, Wkb, Wvb, bk, bv, Qb, ctxb, wacc);
  k_gemm<<<dim3(BT/128, 8), B256, 0, stream>>>(ctxb, 1024, Wob, 1024, 1024, bo, aob, 1024, 0, 0);
  k_ln<<<dim3(BT), B256, 0, stream>>>(aob, nullptr, g1, be1, f1b, nullptr);

  for (int c = 0; c < 4; ++c){
    const u16* fa = f1b + (size_t)c*8192*1024;
    k_gemm<<<dim3(64, 32), B256, 0, stream>>>(fa, 1024, W1b, 1024, 1024, b1, ff1c, 4096, 0, 1);
    k_gemm<<<dim3(64, 8),  B256, 0, stream>>>(ff1c, 4096, W2b, 4096, 4096, b2,
                                              ff2b + (size_t)c*8192*1024, 1024, 0, 0);
  }
  float* outf = (float*)d_out;
  k_ln<<<dim3(BT), B256, 0, stream>>>(ff2b, f1b, g2, be2, nullptr, outf);
  k_copyf<<<dim3(384), B256, 0, stream>>>(wacc, outf + (size_t)BT*1024, BT*3);
}

// Round 2
// 1703.659 us; speedup vs baseline: 1.1927x; 1.1927x over previous
//
#include <hip/hip_runtime.h>
#include <hip/hip_bf16.h>
#include <math.h>

#define BT 32768        // B*T tokens
#define HH 1024

typedef unsigned short u16;
typedef __attribute__((ext_vector_type(4))) unsigned short u16x4;
typedef __attribute__((ext_vector_type(8))) __bf16 bf16x8;
typedef __attribute__((ext_vector_type(4))) float f32x4;

#define DEVI static __device__ __forceinline__

DEVI u16 f2bf(float f){
  unsigned u = __builtin_bit_cast(unsigned, f);
  u += 0x7FFFu + ((u >> 16) & 1u);
  return (u16)(u >> 16);
}
DEVI float bf2f(u16 h){
  unsigned u = ((unsigned)h) << 16;
  return __builtin_bit_cast(float, u);
}
DEVI void gl_lds16(const void* g, void* l){
  __builtin_amdgcn_global_load_lds((const __attribute__((address_space(1))) void*)g,
                                   (__attribute__((address_space(3))) void*)l, 16, 0, 0);
}
// T2 swizzle: 16B-granule XOR within a 64-elem (128B) row. elem units of u16.
DEVI int swz(int row, int elem){ return elem ^ ((row & 7) << 3); }

// ---------------- elementwise prep kernels ----------------
__global__ void k_cast4(const float* __restrict__ s, u16* __restrict__ d, int n4){
  int i = blockIdx.x*blockDim.x + threadIdx.x;
  int st = gridDim.x*blockDim.x;
  for (; i < n4; i += st){
    float4 v = ((const float4*)s)[i];
    u16x4 o = { f2bf(v.x), f2bf(v.y), f2bf(v.z), f2bf(v.w) };
    ((u16x4*)d)[i] = o;
  }
}

// x2 -> stacked slot 2 (ld 3072)
__global__ void k_pack_x2(const float* __restrict__ s, u16* __restrict__ d, int n4){
  int i = blockIdx.x*blockDim.x + threadIdx.x;
  int st = gridDim.x*blockDim.x;
  for (; i < n4; i += st){
    int e = i*4; int t = e >> 10; int c = e & 1023;
    float4 v = *(const float4*)&s[e];
    u16x4 o = { f2bf(v.x), f2bf(v.y), f2bf(v.z), f2bf(v.w) };
    *(u16x4*)&d[(size_t)t*3072 + 2048 + c] = o;
  }
}

// qb = bf16(query_token + static_context)
__global__ void k_qb(const float* __restrict__ qt, const float* __restrict__ sc,
                     u16* __restrict__ d, int n4){
  int i = blockIdx.x*blockDim.x + threadIdx.x;
  int st = gridDim.x*blockDim.x;
  for (; i < n4; i += st){
    int e = i*4; int c = e & 1023;
    float4 v = *(const float4*)&sc[e];
    float4 q = *(const float4*)&qt[c];
    u16x4 o = { f2bf(v.x+q.x), f2bf(v.y+q.y), f2bf(v.z+q.z), f2bf(v.w+q.w) };
    ((u16x4*)d)[i] = o;
  }
}

__global__ void k_copyf(const float* __restrict__ s, float* __restrict__ d, int n){
  int i = blockIdx.x*blockDim.x + threadIdx.x;
  int st = gridDim.x*blockDim.x;
  for (; i < n; i += st) d[i] = s[i];
}

// ---------------- GEMM: C[M,N](bf16) = A[M,K](bf16) @ B[N,K]^T + bias, opt gelu ----------------
__global__ __launch_bounds__(256, 3)
void k_gemm(const u16* __restrict__ A, int lda,
            const u16* __restrict__ B, int ldb, int K,
            const float* __restrict__ bias,
            u16* __restrict__ C, int ldc, int col0, int act)
{
  __shared__ u16 As[128*64];
  __shared__ u16 Bs[128*64];
  const int tid = threadIdx.x, lane = tid & 63, wid = tid >> 6;
  const int wr = wid >> 1, wc = wid & 1;
  const int r15 = lane & 15, g = lane >> 4;
  const int m0 = blockIdx.x * 128, n0 = blockIdx.y * 128;
  f32x4 acc[4][4] = {};

  for (int k0 = 0; k0 < K; k0 += 64){
    #pragma unroll
    for (int it = 0; it < 4; ++it){
      int c = it*256 + tid;
      int row = c >> 3;
      int ke = swz(row, (c & 7) * 8);      // inverse-swizzled global source
      gl_lds16(A + (size_t)(m0+row)*lda + (k0+ke), As + c*8);
      gl_lds16(B + (size_t)(n0+row)*ldb + (k0+ke), Bs + c*8);
    }
    __syncthreads();
    #pragma unroll
    for (int kk = 0; kk < 64; kk += 32){
      bf16x8 av[4], bvv[4];
      #pragma unroll
      for (int i = 0; i < 4; ++i){
        int row = wr*64 + i*16 + r15;
        av[i] = *(const bf16x8*)&As[row*64 + swz(row, kk + g*8)];
      }
      #pragma unroll
      for (int j = 0; j < 4; ++j){
        int row = wc*64 + j*16 + r15;
        bvv[j] = *(const bf16x8*)&Bs[row*64 + swz(row, kk + g*8)];
      }
      #pragma unroll
      for (int i = 0; i < 4; ++i)
        #pragma unroll
        for (int j = 0; j < 4; ++j)
          acc[i][j] = __builtin_amdgcn_mfma_f32_16x16x32_bf16(av[i], bvv[j], acc[i][j], 0, 0, 0);
    }
    __syncthreads();
  }
  #pragma unroll
  for (int j = 0; j < 4; ++j){
    int col = wc*64 + j*16 + r15;
    float bb = bias ? bias[n0 + col] : 0.f;
    #pragma unroll
    for (int i = 0; i < 4; ++i){
      #pragma unroll
      for (int jj = 0; jj < 4; ++jj){
        int row = wr*64 + i*16 + g*4 + jj;
        float v = acc[i][j][jj] + bb;
        if (act == 1) v = 0.5f * v * (1.f + erff(v * 0.70710678118654752f));
        C[(size_t)(m0+row)*ldc + col0 + n0 + col] = f2bf(v);
      }
    }
  }
}

// ---------------- fused K/V projection + M=3 cross-attention ----------------
// block: 32 tokens (96 stacked rows) x 128 cols (2 heads). K,V GEMM tiles in regs,
// then scores -> softmax over 3 modalities -> ctx + head-mean weights in epilogue.
__global__ __launch_bounds__(256, 3)
void k_attn(const u16* __restrict__ S, const u16* __restrict__ Wk, const u16* __restrict__ Wv,
            const float* __restrict__ bk, const float* __restrict__ bv,
            const u16* __restrict__ Q, u16* __restrict__ ctx, float* __restrict__ wacc)
{
  __shared__ __align__(16) char smem[45056];
  u16* As  = (u16*)smem;                    // 96x64
  u16* Bk  = (u16*)(smem + 12288);          // 128x64
  u16* Bv  = (u16*)(smem + 12288 + 16384);  // 128x64
  u16* Vl  = (u16*)smem;                    // epilogue: 96x128 bf16
  u16* Ql  = (u16*)(smem + 24576);          // epilogue: 32x128 bf16
  float* Sl = (float*)(smem + 24576 + 8192);// epilogue: 2 heads x 96 rows

  const int tid = threadIdx.x, lane = tid & 63, wid = tid >> 6;
  const int wr = wid >> 1, wcH = wid & 1;
  const int r15 = lane & 15, g = lane >> 4;
  const int bt = blockIdx.x, bn = blockIdx.y;
  const int row0 = bt * 96, n0 = bn * 128;

  f32x4 aK[3][4] = {}; f32x4 aV[3][4] = {};

  for (int k0 = 0; k0 < 1024; k0 += 64){
    #pragma unroll
    for (int it = 0; it < 3; ++it){
      int c = it*256 + tid; int row = c >> 3;
      int ke = swz(row, (c & 7) * 8);
      gl_lds16(S + (size_t)(row0+row)*1024 + k0 + ke, As + c*8);
    }
    #pragma unroll
    for (int it = 0; it < 4; ++it){
      int c = it*256 + tid; int row = c >> 3;
      int ke = swz(row, (c & 7) * 8);
      gl_lds16(Wk + (size_t)(n0+row)*1024 + k0 + ke, Bk + c*8);
      gl_lds16(Wv + (size_t)(n0+row)*1024 + k0 + ke, Bv + c*8);
    }
    __syncthreads();
    #pragma unroll
    for (int kk = 0; kk < 64; kk += 32){
      bf16x8 av[3], b1[4], b2[4];
      #pragma unroll
      for (int i = 0; i < 3; ++i){
        int row = wr*48 + i*16 + r15;
        av[i] = *(const bf16x8*)&As[row*64 + swz(row, kk + g*8)];
      }
      #pragma unroll
      for (int j = 0; j < 4; ++j){
        int row = wcH*64 + j*16 + r15;
        b1[j] = *(const bf16x8*)&Bk[row*64 + swz(row, kk + g*8)];
        b2[j] = *(const bf16x8*)&Bv[row*64 + swz(row, kk + g*8)];
      }
      #pragma unroll
      for (int i = 0; i < 3; ++i)
        #pragma unroll
        for (int j = 0; j < 4; ++j){
          aK[i][j] = __builtin_amdgcn_mfma_f32_16x16x32_bf16(av[i], b1[j], aK[i][j], 0, 0, 0);
          aV[i][j] = __builtin_amdgcn_mfma_f32_16x16x32_bf16(av[i], b2[j], aV[i][j], 0, 0, 0);
        }
    }
    __syncthreads();
  }

  // V (+bias) -> LDS as bf16
  #pragma unroll
  for (int j = 0; j < 4; ++j){
    int col = wcH*64 + j*16 + r15;
    float bvv = bv[n0 + col];
    #pragma unroll
    for (int i = 0; i < 3; ++i)
      #pragma unroll
      for (int jj = 0; jj < 4; ++jj){
        int row = wr*48 + i*16 + g*4 + jj;
        Vl[row*128 + col] = f2bf(aV[i][j][jj] + bvv);
      }
  }
  // stage Q tile [32 tokens][128 cols]
  #pragma unroll
  for (int it = 0; it < 4; ++it){
    int c4 = it*256 + tid;              // 1024 chunks of 4 elems
    int tt = c4 >> 5, cc = (c4 & 31)*4;
    *(u16x4*)&Ql[tt*128 + cc] = *(const u16x4*)&Q[(size_t)(bt*32 + tt)*1024 + n0 + cc];
  }
  __syncthreads();

  // scores: s[row] = (Q[t,h,:] . (K[row,:]+bk)) / 8 ; d-reduction over 4 col-frags + 16 lanes
  float bkv[4];
  #pragma unroll
  for (int j = 0; j < 4; ++j) bkv[j] = bk[n0 + wcH*64 + j*16 + r15];
  #pragma unroll
  for (int i = 0; i < 3; ++i){
    #pragma unroll
    for (int jj = 0; jj < 4; ++jj){
      int row = wr*48 + i*16 + g*4 + jj;   // 0..95
      int tt = row / 3;
      float s = 0.f;
      #pragma unroll
      for (int j = 0; j < 4; ++j){
        float qv = bf2f(Ql[tt*128 + wcH*64 + j*16 + r15]);
        s += (aK[i][j][jj] + bkv[j]) * qv;
      }
      s += __shfl_xor(s, 1); s += __shfl_xor(s, 2);
      s += __shfl_xor(s, 4); s += __shfl_xor(s, 8);
      if (r15 == 0) Sl[wcH*96 + row] = s * 0.125f;
    }
  }
  __syncthreads();

  // softmax over m=3, ctx, head-averaged weights
  const int t0 = bt*32;
  #pragma unroll
  for (int it = 0; it < 16; ++it){
    int idx = it*256 + tid;
    int tt = idx >> 7, col = idx & 127;
    int h = col >> 6;
    float s0 = Sl[h*96 + tt*3 + 0];
    float s1 = Sl[h*96 + tt*3 + 1];
    float s2 = Sl[h*96 + tt*3 + 2];
    float mx = fmaxf(s0, fmaxf(s1, s2));
    float e0 = expf(s0-mx), e1 = expf(s1-mx), e2 = expf(s2-mx);
    float inv = 1.f/(e0+e1+e2);
    e0 *= inv; e1 *= inv; e2 *= inv;
    float c = e0*bf2f(Vl[(tt*3+0)*128 + col])
            + e1*bf2f(Vl[(tt*3+1)*128 + col])
            + e2*bf2f(Vl[(tt*3+2)*128 + col]);
    ctx[(size_t)(t0+tt)*1024 + n0 + col] = f2bf(c);
    if ((col & 63) == 0){
      atomicAdd(&wacc[(size_t)(t0+tt)*3 + 0], e0*0.0625f);
      atomicAdd(&wacc[(size_t)(t0+tt)*3 + 1], e1*0.0625f);
      atomicAdd(&wacc[(size_t)(t0+tt)*3 + 2], e2*0.0625f);
    }
  }
}

// ---------------- LayerNorm (H=1024), optional bf16 residual, bf16 or f32 out ----------------
__global__ __launch_bounds__(256)
void k_ln(const u16* __restrict__ X, const u16* __restrict__ R,
          const float* __restrict__ gam, const float* __restrict__ bet,
          u16* __restrict__ outb, float* __restrict__ outf)
{
  __shared__ float rs[4], rq[4];
  const int t = blockIdx.x, tid = threadIdx.x;
  const size_t base = (size_t)t*1024 + tid*4;
  u16x4 xv = *(const u16x4*)&X[base];
  float v[4];
  #pragma unroll
  for (int i = 0; i < 4; ++i) v[i] = bf2f(xv[i]);
  if (R){
    u16x4 rv = *(const u16x4*)&R[base];
    #pragma unroll
    for (int i = 0; i < 4; ++i) v[i] += bf2f(rv[i]);
  }
  float s = v[0]+v[1]+v[2]+v[3];
  float q = v[0]*v[0]+v[1]*v[1]+v[2]*v[2]+v[3]*v[3];
  #pragma unroll
  for (int m = 1; m < 64; m <<= 1){ s += __shfl_xor(s, m); q += __shfl_xor(q, m); }
  if ((tid & 63) == 0){ rs[tid>>6] = s; rq[tid>>6] = q; }
  __syncthreads();
  s = rs[0]+rs[1]+rs[2]+rs[3];
  q = rq[0]+rq[1]+rq[2]+rq[3];
  float mean = s * (1.f/1024.f);
  float var  = q * (1.f/1024.f) - mean*mean;
  float rstd = rsqrtf(var + 1e-5f);
  int c0 = tid*4;
  if (outb){
    u16x4 o;
    #pragma unroll
    for (int i = 0; i < 4; ++i) o[i] = f2bf((v[i]-mean)*rstd*gam[c0+i] + bet[c0+i]);
    *(u16x4*)&outb[base] = o;
  } else {
    float4 o;
    o.x = (v[0]-mean)*rstd*gam[c0+0] + bet[c0+0];
    o.y = (v[1]-mean)*rstd*gam[c0+1] + bet[c0+1];
    o.z = (v[2]-mean)*rstd*gam[c0+2] + bet[c0+2];
    o.w = (v[3]-mean)*rstd*gam[c0+3] + bet[c0+3];
    *(float4*)&outf[base] = o;
  }
}

// ---------------- host launcher ----------------
extern "C" void kernel_launch(void* const* d_in, const int* in_sizes, int n_in,
                              void* d_out, int out_size, void* d_ws, size_t ws_size,
                              hipStream_t stream)
{
  (void)in_sizes; (void)n_in; (void)out_size;
  const float* x0  = (const float*)d_in[0];
  const float* x1  = (const float*)d_in[1];
  const float* x2  = (const float*)d_in[2];
  const float* sc  = (const float*)d_in[3];
  const float* Wp0 = (const float*)d_in[4];  const float* bp0 = (const float*)d_in[5];
  const float* Wp1 = (const float*)d_in[6];  const float* bp1 = (const float*)d_in[7];
  const float* Wq  = (const float*)d_in[8];  const float* bq  = (const float*)d_in[9];
  const float* Wk  = (const float*)d_in[10]; const float* bk  = (const float*)d_in[11];
  const float* Wv  = (const float*)d_in[12]; const float* bv  = (const float*)d_in[13];
  const float* Wo  = (const float*)d_in[14]; const float* bo  = (const float*)d_in[15];
  const float* qt  = (const float*)d_in[16];
  const float* g1  = (const float*)d_in[17]; const float* be1 = (const float*)d_in[18];
  const float* g2  = (const float*)d_in[19]; const float* be2 = (const float*)d_in[20];
  const float* W1  = (const float*)d_in[21]; const float* b1  = (const float*)d_in[22];
  const float* W2  = (const float*)d_in[23]; const float* b2  = (const float*)d_in[24];

  char* ws = (char*)d_ws;
  size_t off = 0;
  auto alloc = [&](size_t b)->char*{ char* p = ws + off; off += (b + 255) & ~(size_t)255; return p; };

  u16* Wp0b = (u16*)alloc((size_t)1024*256*2);
  u16* Wp1b = (u16*)alloc((size_t)1024*512*2);
  u16* Wqb  = (u16*)alloc((size_t)1024*1024*2);
  u16* Wkb  = (u16*)alloc((size_t)1024*1024*2);
  u16* Wvb  = (u16*)alloc((size_t)1024*1024*2);
  u16* Wob  = (u16*)alloc((size_t)1024*1024*2);
  u16* W1b  = (u16*)alloc((size_t)4096*1024*2);
  u16* W2b  = (u16*)alloc((size_t)1024*4096*2);
  char* stackedR = alloc((size_t)3*BT*1024*2);   // stacked [3T,1024]; later ff1 chunk
  char* regA = alloc((size_t)BT*1024*2);         // x0b+x1b -> Qb -> attn_out -> ff2
  char* regB = alloc((size_t)BT*1024*2);         // qb -> ctx -> fused1
  float* wacc = (float*)alloc((size_t)BT*3*4);
  if (off > ws_size) return;  // workspace too small; fail visibly

  u16* stackedb = (u16*)stackedR;
  u16* ff1c = (u16*)stackedR;
  u16* x0b = (u16*)regA;
  u16* x1b = (u16*)(regA + (size_t)BT*256*2);
  u16* Qb  = (u16*)regA;
  u16* aob = (u16*)regA;
  u16* ff2b = (u16*)regA;
  u16* qb  = (u16*)regB;
  u16* ctxb = (u16*)regB;
  u16* f1b = (u16*)regB;

  hipMemsetAsync(wacc, 0, (size_t)BT*3*4, stream);

  dim3 B256(256);
  auto cast4 = [&](const float* s, u16* d, int n){
    k_cast4<<<dim3(1024), B256, 0, stream>>>(s, d, n >> 2);
  };
  cast4(Wp0, Wp0b, 1024*256); cast4(Wp1, Wp1b, 1024*512);
  cast4(Wq, Wqb, 1024*1024);  cast4(Wk, Wkb, 1024*1024);
  cast4(Wv, Wvb, 1024*1024);  cast4(Wo, Wob, 1024*1024);
  cast4(W1, W1b, 4096*1024);  cast4(W2, W2b, 4096*1024);
  cast4(x0, x0b, BT*256);     cast4(x1, x1b, BT*512);
  k_pack_x2<<<dim3(2048), B256, 0, stream>>>(x2, stackedb, BT*256);
  k_qb<<<dim3(2048), B256, 0, stream>>>(qt, sc, qb, BT*256);

  k_gemm<<<dim3(BT/128, 8), B256, 0, stream>>>(x0b, 256, Wp0b, 256, 256, bp0, stackedb, 3072, 0,    0);
  k_gemm<<<dim3(BT/128, 8), B256, 0, stream>>>(x1b, 512, Wp1b, 512, 512, bp1, stackedb, 3072, 1024, 0);
  k_gemm<<<dim3(BT/128, 8), B256, 0, stream>>>(qb, 1024, Wqb, 1024, 1024, bq, Qb, 1024, 0, 0);
  k_attn<<<dim3(BT/32, 8), B256, 0, stream>>>(stackedb, Wkb, Wvb, bk, bv, Qb, ctxb, wacc);
  k_gemm<<<dim3(BT/128, 8), B256, 0, stream>>>(ctxb, 1024, Wob, 1024, 1024, bo, aob, 1024, 0, 0);
  k_ln<<<dim3(BT), B256, 0, stream>>>(aob, nullptr, g1, be1, f1b, nullptr);

  for (int c = 0; c < 4; ++c){
    const u16* fa = f1b + (size_t)c*8192*1024;
    k_gemm<<<dim3(64, 32), B256, 0, stream>>>(fa, 1024, W1b, 1024, 1024, b1, ff1c, 4096, 0, 1);
    k_gemm<<<dim3(64, 8),  B256, 0, stream>>>(ff1c, 4096, W2b, 4096, 4096, b2,
                                              ff2b + (size_t)c*8192*1024, 1024, 0, 0);
  }
  float* outf = (float*)d_out;
  k_ln<<<dim3(BT), B256, 0, stream>>>(ff2b, f1b, g2, be2, nullptr, outf);
  k_copyf<<<dim3(384), B256, 0, stream>>>(wacc, outf + (size_t)BT*1024, BT*3);
}